// Round 11
// baseline (80.513 us; speedup 1.0000x reference)
//
#include <hip/hip_runtime.h>

// Problem constants (from reference setup_inputs).
constexpr int B = 8;
constexpr int N = 16384;
constexpr int M = 1024;
constexpr int C = 256;
constexpr int QW = 4;     // candidate quarters (= waves per block)

typedef float vf16 __attribute__((ext_vector_type(16)));

// Block = 256 threads = 4 waves, owns TWO 64-point tiles (128 pts); 1024 blocks.
// Software pipeline: scan(t0) | [phase2(t0) FUSED with scan(t1)] | phase2(t1).
// The fused middle loop issues tile-0 gathers/stores under tile-1 ladder VALU,
// overlapping the memory phase with the compute phase inside one instr stream.
// Phase 1 candidates come from SGPRs via s_load_dwordx16 (SMEM pipe, no LDS).
// All selection math is bit-exact vs the reference ((dx*dx+dy*dy)+dz*dz,
// separately rounded; strict-< ladder = top_k lowest-index tie-break).
// XCD swizzle: batch = blk & 7 pins each batch's 1MB feats to one XCD's L2.
__global__ __launch_bounds__(256, 8) void upsample_idw_kernel(
    const float* __restrict__ xyz,          // [B,N,3]
    const float* __restrict__ sxyz,         // [B,M,3]
    const float* __restrict__ feats,        // [B,M,C]
    const int*   __restrict__ masks,        // [B,N]
    float*       __restrict__ out)          // [B,N,C]
{
    const int tid = threadIdx.x;
    const int w   = tid >> 6;               // wave id = candidate quarter
    const int l   = tid & 63;               // lane = point within tile
    const int blk = blockIdx.x;
    const int b     = blk & 7;              // batch == XCD (round-robin dispatch)
    const int nbase = (blk >> 3) << 7;      // first point (128 per block)

    __shared__ unsigned long long s_key[2][64][QW][3];   // 12KB (double-buffered)
    __shared__ float s_wt[2][64][3];
    __shared__ int   s_j[2][64][4];         // j0, j1, j2, valid

    // BLOCK-uniform batch base (SGPR pair for s_load); wave offset via
    // readfirstlane into the SMEM soffset operand.
    const float* bbase = sxyz + (size_t)b * (M * 3);
    const int qoff = __builtin_amdgcn_readfirstlane((tid >> 6) * (256 * 12));

    // Both tiles' point coords.
    const float* xp0 = xyz + ((size_t)b * N + nbase + l) * 3;
    const float* xp1 = xyz + ((size_t)b * N + nbase + 64 + l) * 3;
    const float x0 = xp0[0], y0 = xp0[1], z0 = xp0[2];
    const float x1 = xp1[0], y1 = xp1[1], z1 = xp1[2];

    const float4* Fb4 = (const float4*)(feats + (size_t)b * (M * C));
    float4* op40 = (float4*)(out + (((size_t)b * N + nbase) * C));
    float4* op41 = (float4*)(out + (((size_t)b * N + nbase + 64) * C));

    // ---- One 16-candidate SMEM chunk through the bit-exact ladder ----
    auto scan_chunk = [&](int ch, float px, float py, float pz,
                          float& d0, float& d1, float& d2,
                          int& i0, int& i1, int& i2) {
        vf16 ca, cb, cc;                    // 48 floats = 16 candidates in SGPRs
        const int off = qoff + ch * 192;
        asm volatile(
            "s_load_dwordx16 %0, %3, %4\n\t"
            "s_load_dwordx16 %1, %3, %4 offset:64\n\t"
            "s_load_dwordx16 %2, %3, %4 offset:128\n\t"
            "s_waitcnt lgkmcnt(0)"
            : "=&s"(ca), "=&s"(cb), "=&s"(cc)
            : "s"(bbase), "s"(off));
        #pragma unroll
        for (int j = 0; j < 16; ++j) {
            const int f0 = 3 * j, f1 = 3 * j + 1, f2 = 3 * j + 2;
            const float cx = (f0 < 16) ? ca[f0 & 15] : (f0 < 32) ? cb[f0 & 15] : cc[f0 & 15];
            const float cy = (f1 < 16) ? ca[f1 & 15] : (f1 < 32) ? cb[f1 & 15] : cc[f1 & 15];
            const float cz = (f2 < 16) ? ca[f2 & 15] : (f2 < 32) ? cb[f2 & 15] : cc[f2 & 15];
            // (c - x): negated dx, identical after squaring.
            const float dx = __fsub_rn(cx, px);
            const float dy = __fsub_rn(cy, py);
            const float dz = __fsub_rn(cz, pz);
            const float d  = __fadd_rn(__fadd_rn(__fmul_rn(dx, dx), __fmul_rn(dy, dy)),
                                       __fmul_rn(dz, dz));
            const int m = ch * 16 + j;
            const bool lt0 = d < d0, lt1 = d < d1, lt2 = d < d2;
            i2 = lt1 ? i1 : (lt2 ? m : i2);
            i1 = lt0 ? i0 : (lt1 ? m : i1);
            i0 = lt0 ? m  : i0;
            const float nd2 = __builtin_amdgcn_fmed3f(d1, d2, d);
            const float nd1 = __builtin_amdgcn_fmed3f(d0, d1, d);
            d2 = nd2; d1 = nd1; d0 = fminf(d0, d);
        }
    };

    auto store_keys = [&](int t, float d0, float d1, float d2,
                          int i0, int i1, int i2) {
        const unsigned base = (unsigned)(w * 256);
        s_key[t][l][w][0] = ((unsigned long long)__float_as_uint(d0) << 32) | (base + (unsigned)i0);
        s_key[t][l][w][1] = ((unsigned long long)__float_as_uint(d1) << 32) | (base + (unsigned)i1);
        s_key[t][l][w][2] = ((unsigned long long)__float_as_uint(d2) << 32) | (base + (unsigned)i2);
    };

    auto merge = [&](int t) {
        if (tid < 64) {
            unsigned long long k0 = ~0ULL, k1 = ~0ULL, k2 = ~0ULL;
            #pragma unroll
            for (int q = 0; q < QW; ++q) {
                #pragma unroll
                for (int s = 0; s < 3; ++s) {
                    const unsigned long long k = s_key[t][tid][q][s];
                    const bool lt0 = k < k0, lt1 = k < k1, lt2 = k < k2;
                    k2 = lt1 ? k1 : (lt2 ? k : k2);
                    k1 = lt0 ? k0 : (lt1 ? k : k1);
                    k0 = lt0 ? k  : k0;
                }
            }
            const float e0 = __uint_as_float((unsigned)(k0 >> 32));
            const float e1 = __uint_as_float((unsigned)(k1 >> 32));
            const float e2 = __uint_as_float((unsigned)(k2 >> 32));
            const float m0 = fmaxf(e0, 1e-10f);
            const float m1 = fmaxf(e1, 1e-10f);
            const float m2 = fmaxf(e2, 1e-10f);
            float w0 = 1.0f / (m0 * m0 + 1e-10f);
            float w1 = 1.0f / (m1 * m1 + 1e-10f);
            float w2 = 1.0f / (m2 * m2 + 1e-10f);
            const int valid = masks[(size_t)b * N + nbase + t * 64 + tid];
            const float scale = valid ? (1.0f / (w0 + w1 + w2)) : 0.0f;
            s_wt[t][tid][0] = w0 * scale;
            s_wt[t][tid][1] = w1 * scale;
            s_wt[t][tid][2] = w2 * scale;
            s_j[t][tid][0] = (int)(unsigned)k0;
            s_j[t][tid][1] = (int)(unsigned)k1;
            s_j[t][tid][2] = (int)(unsigned)k2;
            s_j[t][tid][3] = valid;
        }
    };

    auto phase2_iter = [&](int t, int i, float4* op4) {
        const int p = 4 * i + w;             // wave-uniform point
        const int vld = __builtin_amdgcn_readfirstlane(s_j[t][p][3]);
        float4 acc = make_float4(0.f, 0.f, 0.f, 0.f);
        if (vld) {                           // scalar branch
            const int j0 = __builtin_amdgcn_readfirstlane(s_j[t][p][0]);
            const int j1 = __builtin_amdgcn_readfirstlane(s_j[t][p][1]);
            const int j2 = __builtin_amdgcn_readfirstlane(s_j[t][p][2]);
            const float u0 = __uint_as_float(
                __builtin_amdgcn_readfirstlane((int)__float_as_uint(s_wt[t][p][0])));
            const float u1 = __uint_as_float(
                __builtin_amdgcn_readfirstlane((int)__float_as_uint(s_wt[t][p][1])));
            const float u2 = __uint_as_float(
                __builtin_amdgcn_readfirstlane((int)__float_as_uint(s_wt[t][p][2])));
            const float4 f0 = Fb4[j0 * 64 + l];
            const float4 f1 = Fb4[j1 * 64 + l];
            const float4 f2 = Fb4[j2 * 64 + l];
            acc.x = fmaf(u2, f2.x, fmaf(u1, f1.x, u0 * f0.x));
            acc.y = fmaf(u2, f2.y, fmaf(u1, f1.y, u0 * f0.y));
            acc.z = fmaf(u2, f2.z, fmaf(u1, f1.z, u0 * f0.z));
            acc.w = fmaf(u2, f2.w, fmaf(u1, f1.w, u0 * f0.w));
        }
        op4[p * 64 + l] = acc;
    };

    // ---- Step 1: scan tile 0 ----
    {
        float d0 = __builtin_inff(), d1 = __builtin_inff(), d2 = __builtin_inff();
        int   i0 = 0, i1 = 0, i2 = 0;
        for (int ch = 0; ch < 16; ++ch)
            scan_chunk(ch, x0, y0, z0, d0, d1, d2, i0, i1, i2);
        store_keys(0, d0, d1, d2, i0, i1, i2);
    }
    __syncthreads();
    merge(0);
    __syncthreads();

    // ---- Step 2: FUSED phase2(tile0) + scan(tile1) ----
    {
        float d0 = __builtin_inff(), d1 = __builtin_inff(), d2 = __builtin_inff();
        int   i0 = 0, i1 = 0, i2 = 0;
        for (int i = 0; i < 16; ++i) {
            phase2_iter(0, i, op40);         // t0 gathers+stores (VMEM)...
            scan_chunk(i, x1, y1, z1, d0, d1, d2, i0, i1, i2);  // ...under t1 VALU
        }
        store_keys(1, d0, d1, d2, i0, i1, i2);
    }
    __syncthreads();
    merge(1);
    __syncthreads();

    // ---- Step 3: phase2 tile 1 ----
    for (int i = 0; i < 16; ++i)
        phase2_iter(1, i, op41);
}

extern "C" void kernel_launch(void* const* d_in, const int* in_sizes, int n_in,
                              void* d_out, int out_size, void* d_ws, size_t ws_size,
                              hipStream_t stream) {
    const float* xyz   = (const float*)d_in[0];
    const float* sxyz  = (const float*)d_in[1];
    const float* feats = (const float*)d_in[2];
    const int*   masks = (const int*)d_in[3];
    float*       out   = (float*)d_out;

    dim3 grid(B * N / 128);   // 1024 blocks
    dim3 block(256);
    hipLaunchKernelGGL(upsample_idw_kernel, grid, block, 0, stream,
                       xyz, sxyz, feats, masks, out);
}